// Round 1
// 35622.818 us; speedup vs baseline: 1.4867x; 1.4867x over previous
//
#include <hip/hip_runtime.h>

#define NTHREADS 1024
#define NB 256
#define TT 64
#define NV 19

// LDS layout (floats, all 16B-aligned offsets):
//  Sm:364  h0:2432  h1:2432  cur:1904  xs:4864  m1:4864  m2:4864  gb:4864  cb:2432  = 29020 floats = 116KB
// NOTE: xs, m1, m2 MUST stay contiguous (gemm_cols indexes mat = xs + kp*4864).

// ---- diffusion build: dst[n][0:256) = S @ src   (or 2*(S@src) - sub if sub != null)
// 16 waves: wave w owns rows {w, w+16}; 64 lanes cover the 256-float row as float4
__device__ __forceinline__ void diffuse(const float* Sm, const float* src, float* dst,
                                        const float* sub, int tid)
{
    const int w = tid >> 6;
    const int c4 = (tid & 63) << 2;
    const int n0 = w, n1 = w + 16;
    float4 a0 = {0.f, 0.f, 0.f, 0.f};
    float4 a1 = {0.f, 0.f, 0.f, 0.f};
#pragma unroll 1
    for (int m = 0; m < 19; ++m) {
        const float4 x4 = *(const float4*)(src + (m << 8) + c4);
        const float s0 = Sm[n0 * 19 + m];
        a0.x += s0 * x4.x; a0.y += s0 * x4.y; a0.z += s0 * x4.z; a0.w += s0 * x4.w;
        if (n1 < 19) {
            const float s1 = Sm[n1 * 19 + m];
            a1.x += s1 * x4.x; a1.y += s1 * x4.y; a1.z += s1 * x4.z; a1.w += s1 * x4.w;
        }
    }
    if (sub) {
        const float4 u0 = *(const float4*)(sub + (n0 << 8) + c4);
        a0.x = 2.f * a0.x - u0.x; a0.y = 2.f * a0.y - u0.y;
        a0.z = 2.f * a0.z - u0.z; a0.w = 2.f * a0.w - u0.w;
        if (n1 < 19) {
            const float4 u1 = *(const float4*)(sub + (n1 << 8) + c4);
            a1.x = 2.f * a1.x - u1.x; a1.y = 2.f * a1.y - u1.y;
            a1.z = 2.f * a1.z - u1.z; a1.w = 2.f * a1.w - u1.w;
        }
    }
    *(float4*)(dst + (n0 << 8) + c4) = a0;
    if (n1 < 19) *(float4*)(dst + (n1 << 8) + c4) = a1;
}

// ---- out(19 x J) += [k-interleaved stack of xs,m1,m2](19 x 3D) @ W(3D x J)
// Ownership GEMM: thread owns one output column j for ALL 19 rows (acc[19], statically
// indexed -> pure VGPR, no spill). K split NKQ-way across thread groups; each W element
// is loaded exactly once per block; LDS x-reads are wave-uniform broadcasts.
// Lanes within a wave = 64 consecutive j -> weight loads perfectly coalesced.
template <int J, int NKQ>
__device__ __forceinline__ void gemm_cols(const float* xs,
                                          const float* __restrict__ W, int D,
                                          float* outb, int tid)
{
    constexpr int DPT = 256 / NKQ;       // d-rows per thread per matrix
    const int j = tid & (J - 1);
    const int kq = tid / J;
    const int kbase = kq * DPT;
    float acc[19];
#pragma unroll
    for (int n = 0; n < 19; ++n) acc[n] = 0.f;

#pragma unroll 1
    for (int kp = 0; kp < 3; ++kp) {
        const float* mat = xs + kp * 4864;    // xs / m1 / m2 (contiguous in LDS)
#pragma unroll 2
        for (int g = 0; g < DPT / 4; ++g) {
            const int d0 = kbase + (g << 2);
            // rows are (3*d + kp): matrix-minor interleave, row stride J
            const float w0 = (d0 + 0 < D) ? W[(size_t)(3 * (d0 + 0) + kp) * J + j] : 0.f;
            const float w1 = (d0 + 1 < D) ? W[(size_t)(3 * (d0 + 1) + kp) * J + j] : 0.f;
            const float w2 = (d0 + 2 < D) ? W[(size_t)(3 * (d0 + 2) + kp) * J + j] : 0.f;
            const float w3 = (d0 + 3 < D) ? W[(size_t)(3 * (d0 + 3) + kp) * J + j] : 0.f;
#pragma unroll
            for (int n = 0; n < 19; ++n) {
                const float4 x4 = *(const float4*)(mat + (n << 8) + d0);  // broadcast
                acc[n] += x4.x * w0;
                acc[n] += x4.y * w1;
                acc[n] += x4.z * w2;
                acc[n] += x4.w * w3;
            }
        }
    }
#pragma unroll
    for (int n = 0; n < 19; ++n)
        atomicAdd(outb + n * J + j, acc[n]);   // NKQ-way reduction, ds_add_f32
}

// ---- projection GEMM: cb(19 x 100, stride 128) += h1(19 x 128) @ Wp(128 x 100)
__device__ __forceinline__ void proj_gemm(const float* h1, const float* __restrict__ Wp,
                                          float* outb, int tid)
{
    const int j = tid & 127;          // 128 col slots, 100 active
    const int kq = tid >> 7;          // 8 K-groups x 16 rows
    const int kbase = kq << 4;
    float acc[19];
#pragma unroll
    for (int n = 0; n < 19; ++n) acc[n] = 0.f;
#pragma unroll 2
    for (int g = 0; g < 4; ++g) {
        const int d0 = kbase + (g << 2);
        const float w0 = (j < 100) ? Wp[(d0 + 0) * 100 + j] : 0.f;
        const float w1 = (j < 100) ? Wp[(d0 + 1) * 100 + j] : 0.f;
        const float w2 = (j < 100) ? Wp[(d0 + 2) * 100 + j] : 0.f;
        const float w3 = (j < 100) ? Wp[(d0 + 3) * 100 + j] : 0.f;
#pragma unroll
        for (int n = 0; n < 19; ++n) {
            const float4 x4 = *(const float4*)(h1 + (n << 7) + d0);  // broadcast
            acc[n] += x4.x * w0;
            acc[n] += x4.y * w1;
            acc[n] += x4.z * w2;
            acc[n] += x4.w * w3;
        }
    }
    if (j < 100) {
#pragma unroll
        for (int n = 0; n < 19; ++n)
            atomicAdd(outb + (n << 7) + j, acc[n]);
    }
}

// ---- one DCGRU cell: h <- u*h + (1-u)*tanh(dconv(x, r*h))
__device__ __forceinline__ void cell(
    int Dx, const float* x, float* h,
    const float* __restrict__ Wg, const float* __restrict__ bg,
    const float* __restrict__ Wc, const float* __restrict__ bc,
    const float* Sm, float* xs, float* m1, float* m2, float* gb, float* cb, int tid)
{
    const int D = Dx + 128;
    // stage xs = [x | h], zero-pad to 256; init gates buffer with bias
    for (int i = tid; i < NV * 256; i += NTHREADS) {
        const int n = i >> 8, d = i & 255;
        float v = 0.f;
        if (d < Dx) v = x[n * Dx + d];
        else if (d < D) v = h[(n << 7) + (d - Dx)];
        xs[i] = v;
        gb[i] = bg[d];
    }
    __syncthreads();
    diffuse(Sm, xs, m1, nullptr, tid);
    __syncthreads();
    diffuse(Sm, m1, m2, xs, tid);
    __syncthreads();
    gemm_cols<256, 4>(xs, Wg, D, gb, tid);
    __syncthreads();
    // sigmoid; write r*h into xs h-part; init cand buffer with bias
    for (int i = tid; i < NV * 256; i += NTHREADS) {
        const int n = i >> 8, j = i & 255;
        const float sg = 1.f / (1.f + __expf(-gb[i]));
        gb[i] = sg;
        if (j < 128) {
            xs[(n << 8) + Dx + j] = sg * h[(n << 7) + j];
            cb[(n << 7) + j] = bc[j];
        }
    }
    __syncthreads();
    diffuse(Sm, xs, m1, nullptr, tid);
    __syncthreads();
    diffuse(Sm, m1, m2, xs, tid);
    __syncthreads();
    gemm_cols<128, 8>(xs, Wc, D, cb, tid);
    __syncthreads();
    // h update: u in gb[:,128:256], c = tanh(cb)
    for (int i = tid; i < NV * 128; i += NTHREADS) {
        const int n = i >> 7, j = i & 127;
        const float u = gb[(n << 8) + 128 + j];
        const float e = __expf(-2.f * cb[i]);
        const float cv = (1.f - e) / (1.f + e);
        h[i] = u * h[i] + (1.f - u) * cv;
    }
    __syncthreads();
}

__global__ __launch_bounds__(NTHREADS) void dcrnn_kernel(
    const float* __restrict__ enc, const float* __restrict__ sup,
    const float* e0Wg, const float* e0bg, const float* e0Wc, const float* e0bc,
    const float* e1Wg, const float* e1bg, const float* e1Wc, const float* e1bc,
    const float* d0Wg, const float* d0bg, const float* d0Wc, const float* d0bc,
    const float* d1Wg, const float* d1bg, const float* d1Wc, const float* d1bc,
    const float* Wp, const float* bp, float* __restrict__ out)
{
    __shared__ __align__(16) float lds[29020];
    float* Sm  = lds;           // 364
    float* h0  = Sm + 364;      // 2432
    float* h1  = h0 + 2432;     // 2432
    float* cur = h1 + 2432;     // 1904
    float* xs  = cur + 1904;    // 4864
    float* m1  = xs + 4864;     // 4864  (contiguous after xs)
    float* m2  = m1 + 4864;     // 4864  (contiguous after m1)
    float* gb  = m2 + 4864;     // 4864
    float* cb  = gb + 4864;     // 2432

    const int tid = threadIdx.x;
    const int b = blockIdx.x;

    for (int i = tid; i < 361; i += NTHREADS) Sm[i] = sup[i];
    for (int i = tid; i < 2432; i += NTHREADS) { h0[i] = 0.f; h1[i] = 0.f; }
    for (int i = tid; i < 1900; i += NTHREADS) cur[i] = 0.f;
    __syncthreads();

    // encoder: two stacked DCGRU layers, interleaved per timestep
    for (int t = 0; t < TT; ++t) {
        const float* xg = enc + ((size_t)b * TT + t) * (NV * 100);
        cell(100, xg, h0, e0Wg, e0bg, e0Wc, e0bc, Sm, xs, m1, m2, gb, cb, tid);
        cell(128, h0, h1, e1Wg, e1bg, e1Wc, e1bc, Sm, xs, m1, m2, gb, cb, tid);
    }
    // decoder: autoregressive, feedback through LDS `cur`
    for (int t = 0; t < TT; ++t) {
        cell(100, cur, h0, d0Wg, d0bg, d0Wc, d0bc, Sm, xs, m1, m2, gb, cb, tid);
        cell(128, h0, h1, d1Wg, d1bg, d1Wc, d1bc, Sm, xs, m1, m2, gb, cb, tid);
        // projection: proj = h1 @ Wp + bp  (into cb, stride 128)
        for (int i = tid; i < NV * 128; i += NTHREADS) {
            const int o = i & 127;
            cb[i] = (o < 100) ? bp[o] : 0.f;
        }
        __syncthreads();
        proj_gemm(h1, Wp, cb, tid);
        __syncthreads();
        float* po = out + ((size_t)b * TT + t) * (NV * 100);
        for (int i = tid; i < NV * 100; i += NTHREADS) {
            const int n = i / 100;
            const int o = i - n * 100;
            const float v = cb[(n << 7) + o];
            po[i] = v;
            cur[i] = v;
        }
        __syncthreads();
    }
}

extern "C" void kernel_launch(void* const* d_in, const int* in_sizes, int n_in,
                              void* d_out, int out_size, void* d_ws, size_t ws_size,
                              hipStream_t stream)
{
    const float* enc  = (const float*)d_in[0];
    // d_in[1] = decoder_inputs: values unused by the reference (autoregressive feedback)
    const float* sup  = (const float*)d_in[2];
    const float* e0Wg = (const float*)d_in[3];
    const float* e0bg = (const float*)d_in[4];
    const float* e0Wc = (const float*)d_in[5];
    const float* e0bc = (const float*)d_in[6];
    const float* e1Wg = (const float*)d_in[7];
    const float* e1bg = (const float*)d_in[8];
    const float* e1Wc = (const float*)d_in[9];
    const float* e1bc = (const float*)d_in[10];
    const float* d0Wg = (const float*)d_in[11];
    const float* d0bg = (const float*)d_in[12];
    const float* d0Wc = (const float*)d_in[13];
    const float* d0bc = (const float*)d_in[14];
    const float* d1Wg = (const float*)d_in[15];
    const float* d1bg = (const float*)d_in[16];
    const float* d1Wc = (const float*)d_in[17];
    const float* d1bc = (const float*)d_in[18];
    const float* Wp   = (const float*)d_in[19];
    const float* bp   = (const float*)d_in[20];

    dcrnn_kernel<<<dim3(NB), dim3(NTHREADS), 0, stream>>>(
        enc, sup,
        e0Wg, e0bg, e0Wc, e0bc, e1Wg, e1bg, e1Wc, e1bc,
        d0Wg, d0bg, d0Wc, d0bc, d1Wg, d1bg, d1Wc, d1bc,
        Wp, bp, (float*)d_out);
}